// Round 1
// baseline (423.150 us; speedup 1.0000x reference)
//
#include <hip/hip_runtime.h>
#include <stdint.h>

#define D_IN  4096
#define D_OUT 4096
#define M_TOT 8192      // B*S = 4*2048

#define BM 128
#define BN 128
#define BK 64

using i32x4 = __attribute__((ext_vector_type(4))) int;

// ---------------------------------------------------------------------------
// Kernel 1: per-row activation fake-quant. One block (256 thr) per row of 4096.
// Writes qx (int8, packed) and s[row] = max|x|/127 + 1e-8.
// ---------------------------------------------------------------------------
__global__ __launch_bounds__(256) void quant_rows(
    const float* __restrict__ x, int8_t* __restrict__ xq,
    float* __restrict__ s_out)
{
    __shared__ float wmax[4];
    const int row = blockIdx.x;
    const int tid = threadIdx.x;
    const float* xr = x + (size_t)row * D_IN;

    float4 v[4];
    float m = 0.f;
#pragma unroll
    for (int c = 0; c < 4; ++c) {
        v[c] = ((const float4*)xr)[c * 256 + tid];
        m = fmaxf(m, fmaxf(fmaxf(fabsf(v[c].x), fabsf(v[c].y)),
                           fmaxf(fabsf(v[c].z), fabsf(v[c].w))));
    }
    // wave (64-lane) butterfly reduce, then cross-wave via LDS
#pragma unroll
    for (int off = 1; off < 64; off <<= 1)
        m = fmaxf(m, __shfl_xor(m, off));
    if ((tid & 63) == 0) wmax[tid >> 6] = m;
    __syncthreads();
    m = fmaxf(fmaxf(wmax[0], wmax[1]), fmaxf(wmax[2], wmax[3]));

    const float s = m / 127.0f + 1e-8f;   // matches reference fp32 arithmetic
    if (tid == 0) s_out[row] = s;

    int* q32 = (int*)(xq + (size_t)row * D_IN);
#pragma unroll
    for (int c = 0; c < 4; ++c) {
        // round-half-even like jnp.round
        int q0 = (int)rintf(v[c].x / s);
        int q1 = (int)rintf(v[c].y / s);
        int q2 = (int)rintf(v[c].z / s);
        int q3 = (int)rintf(v[c].w / s);
        q32[c * 256 + tid] = (q0 & 0xff) | ((q1 & 0xff) << 8) |
                             ((q2 & 0xff) << 16) | ((q3 & 0xff) << 24);
    }
}

// ---------------------------------------------------------------------------
// Kernel 2: pack weight (delivered as int32 per harness integer contract)
// into int8. Each thread: 4 consecutive int32 -> one int32 of 4 int8 bytes.
// ---------------------------------------------------------------------------
__global__ __launch_bounds__(256) void pack_w(
    const int* __restrict__ w32, int8_t* __restrict__ w8, int n4)
{
    int i = blockIdx.x * blockDim.x + threadIdx.x;
    if (i >= n4) return;
    int4 v = ((const int4*)w32)[i];
    ((int*)w8)[i] = (v.x & 0xff) | ((v.y & 0xff) << 8) |
                    ((v.z & 0xff) << 16) | ((v.w & 0xff) << 24);
}

// ---------------------------------------------------------------------------
// Kernel 3: int8 GEMM  Y[M][N] = (qx[M][K] . qw[N][K]^T) * (s[m]*wscale) + bias
// 128x128 tile, BK=64, 4 waves (2x2), mfma_i32_16x16x64_i8.
// m97 structure: global_load_lds width-16 staging, ds_read_b128 fragments.
// ---------------------------------------------------------------------------
__device__ __forceinline__ void gload_lds16(const void* g, void* l) {
    __builtin_amdgcn_global_load_lds(
        (const __attribute__((address_space(1))) unsigned int*)(uintptr_t)g,
        (__attribute__((address_space(3))) unsigned int*)(uintptr_t)l,
        16, 0, 0);
}

__global__ __launch_bounds__(256) void gemm_i8(
    const int8_t* __restrict__ Aq, const int8_t* __restrict__ Wq,
    const float* __restrict__ srow, const float* __restrict__ wsc,
    const float* __restrict__ bias, float* __restrict__ Y)
{
    __shared__ int8_t lA[BM * BK];   // 8 KiB
    __shared__ int8_t lB[BN * BK];   // 8 KiB

    const int tid  = threadIdx.x;
    const int lane = tid & 63;
    const int wave = tid >> 6;
    const int nbx  = D_OUT / BN;                 // 32
    const int bn   = (blockIdx.x % nbx) * BN;
    const int bm   = (blockIdx.x / nbx) * BM;
    const int wr   = (wave >> 1) * 64;           // wave sub-tile origin (rows)
    const int wc   = (wave & 1) * 64;            // wave sub-tile origin (cols)

    i32x4 acc[4][4] = {};

    // fragment read coords: A row = lane&15, k-group = (lane>>4)*16
    const int fr = lane & 15;
    const int fk = (lane >> 4) * 16;

    const int8_t* gA = Aq + (size_t)bm * D_IN;
    const int8_t* gW = Wq + (size_t)bn * D_IN;

    for (int kt = 0; kt < D_IN; kt += BK) {
        // stage A and B tiles: 512 chunks of 16B each, 2 per thread per tile.
        // LDS dest is linear (chunk c at byte c*16) = wave-uniform base + lane*16.
#pragma unroll
        for (int j = 0; j < 2; ++j) {
            const int c  = j * 256 + tid;
            const int r  = c >> 2;
            const int ko = (c & 3) * 16;
            gload_lds16(gA + (size_t)r * D_IN + kt + ko, lA + c * 16);
            gload_lds16(gW + (size_t)r * D_IN + kt + ko, lB + c * 16);
        }
        __syncthreads();   // compiler drains vmcnt before barrier

        i32x4 a[4], b[4];
#pragma unroll
        for (int i = 0; i < 4; ++i) {
            a[i] = *(const i32x4*)(lA + (wr + i * 16 + fr) * BK + fk);
            b[i] = *(const i32x4*)(lB + (wc + i * 16 + fr) * BK + fk);
        }
#pragma unroll
        for (int i = 0; i < 4; ++i)
#pragma unroll
            for (int j = 0; j < 4; ++j)
                acc[i][j] = __builtin_amdgcn_mfma_i32_16x16x64_i8(
                    a[i], b[j], acc[i][j], 0, 0, 0);
        __syncthreads();
    }

    // Epilogue: y = acc * (s[m]*wscale) + bias[n]
    // C/D layout: col = lane&15, row = (lane>>4)*4 + reg  (dtype-independent)
    const float ws = wsc[0];
    float bs[4];
#pragma unroll
    for (int j = 0; j < 4; ++j) bs[j] = bias[bn + wc + j * 16 + fr];

#pragma unroll
    for (int i = 0; i < 4; ++i) {
        const int m0 = bm + wr + i * 16 + (lane >> 4) * 4;
#pragma unroll
        for (int r = 0; r < 4; ++r) {
            const float sm = srow[m0 + r] * ws;
            float* yp = Y + (size_t)(m0 + r) * D_OUT + bn + wc + fr;
#pragma unroll
            for (int j = 0; j < 4; ++j)
                yp[j * 16] = (float)acc[i][j][r] * sm + bs[j];
        }
    }
}

// ---------------------------------------------------------------------------
extern "C" void kernel_launch(void* const* d_in, const int* in_sizes, int n_in,
                              void* d_out, int out_size, void* d_ws, size_t ws_size,
                              hipStream_t stream) {
    const float* x    = (const float*)d_in[0];
    const int*   w32  = (const int*)d_in[1];     // int8 values widened to int32
    const float* wsc  = (const float*)d_in[2];
    const float* bias = (const float*)d_in[3];
    float* y = (float*)d_out;

    // workspace layout: qx (32 MiB) | w8 (16 MiB) | s (32 KiB)
    int8_t* xq = (int8_t*)d_ws;
    int8_t* w8 = xq + (size_t)M_TOT * D_IN;
    float*  s  = (float*)(w8 + (size_t)D_OUT * D_IN);

    quant_rows<<<M_TOT, 256, 0, stream>>>(x, xq, s);

    const int n4 = (D_OUT * D_IN) / 4;
    pack_w<<<(n4 + 255) / 256, 256, 0, stream>>>(w32, w8, n4);

    gemm_i8<<<(M_TOT / BM) * (D_OUT / BN), 256, 0, stream>>>(xq, w8, s, wsc, bias, y);
}